// Round 1
// baseline (2552.762 us; speedup 1.0000x reference)
//
#include <hip/hip_runtime.h>
#include <stdint.h>

// Problem constants (SimpleRNN reference)
#define VOCAB 50000
#define D     512
#define LSEQ  512
#define BATCH 256
#define NCLS  20

typedef unsigned short u16;
using f32x4 = __attribute__((ext_vector_type(4))) float;
using s16x8 = __attribute__((ext_vector_type(8))) short;

__device__ __forceinline__ float bf2f(u16 u){
  union { uint32_t i; float f; } v; v.i = ((uint32_t)u) << 16; return v.f;
}
__device__ __forceinline__ u16 f2bf(float f){
  uint32_t x = __float_as_uint(f);
  x += 0x7fffu + ((x >> 16) & 1u);          // RNE (values are tame, no NaN path)
  return (u16)(x >> 16);
}
// tanh via v_exp_f32 + v_rcp_f32 (~5 VALU ops); saturates correctly at +/-inf.
__device__ __forceinline__ float fast_tanh(float x){
  float e = __builtin_amdgcn_exp2f(x * 2.8853900817779268f);   // e^(2x)
  return 1.0f - 2.0f * __builtin_amdgcn_rcpf(1.0f + e);
}

// ---------------------------------------------------------------------------
// Kernel 0: transpose + bf16-convert Wx and Wh -> Wxt/Wht [n][k] layout so
// MFMA B/A fragments (8 contiguous k per lane) are 16B vector loads.
// ---------------------------------------------------------------------------
__global__ void k_transpose_cvt(const float* __restrict__ Wx, const float* __restrict__ Wh,
                                u16* __restrict__ Wxt, u16* __restrict__ Wht){
  const int n = blockIdx.x & 511;
  const float* src = (blockIdx.x >> 9) ? Wh : Wx;
  u16* dst = (blockIdx.x >> 9) ? Wht : Wxt;
  for (int k = threadIdx.x; k < D; k += blockDim.x)
    dst[n * D + k] = f2bf(src[k * D + n]);   // strided read, coalesced write; ~1.5MB total
}

// ---------------------------------------------------------------------------
// Kernel 1: xin[l][b][:] = emb[x[b][l]] @ Wx + b   (stored bf16, [L][B][D])
// Block: 256 thr (4 waves), M-tile 64 rows (wave: 16 rows), N = full 512.
// A fragments straight from emb (gather, fp32->bf16 in-reg); B staged in LDS.
// ---------------------------------------------------------------------------
__launch_bounds__(256, 2)
__global__ void k_xin(const int* __restrict__ x, const float* __restrict__ emb,
                      const u16* __restrict__ Wxt, const float* __restrict__ bias,
                      u16* __restrict__ xin){
  __shared__ __align__(16) u16 Bt_s[512 * 40];   // [n][32k + 8 pad] bf16, 40KB
  __shared__ int tok_s[64];
  const int tid  = threadIdx.x;
  const int lane = tid & 63, w = tid >> 6;
  const int nl   = lane & 15, q = lane >> 4;
  const int m0   = blockIdx.x * 64;

  if (tid < 64){
    int R = m0 + tid;                 // global row = l*256 + b
    int l = R >> 8, b = R & 255;
    tok_s[tid] = x[b * LSEQ + l];     // x is [B][L]
  }
  f32x4 acc[32];
  #pragma unroll
  for (int i = 0; i < 32; ++i) acc[i] = (f32x4)0.0f;
  __syncthreads();

  const int myrow = 16 * w + nl;                  // A-row m this lane feeds
  const float* arow = emb + (size_t)tok_s[myrow] * D;

  for (int kc = 0; kc < 16; ++kc){
    // stage Wxt[:, k-chunk] -> LDS (already bf16: raw 16B copies)
    #pragma unroll
    for (int i = 0; i < 8; ++i){
      int idx = tid + 256 * i;
      int r = idx >> 2, cc = idx & 3;
      *(uint4*)&Bt_s[r * 40 + cc * 8] = *(const uint4*)(Wxt + r * D + kc * 32 + cc * 8);
    }
    __syncthreads();
    // A fragment: 8 consecutive k of emb row (fp32 -> bf16)
    float4 f0 = *(const float4*)(arow + kc * 32 + q * 8);
    float4 f1 = *(const float4*)(arow + kc * 32 + q * 8 + 4);
    s16x8 a;
    a[0]=(short)f2bf(f0.x); a[1]=(short)f2bf(f0.y); a[2]=(short)f2bf(f0.z); a[3]=(short)f2bf(f0.w);
    a[4]=(short)f2bf(f1.x); a[5]=(short)f2bf(f1.y); a[6]=(short)f2bf(f1.z); a[7]=(short)f2bf(f1.w);
    #pragma unroll
    for (int nt = 0; nt < 32; ++nt){
      s16x8 b = *(const s16x8*)&Bt_s[(16 * nt + nl) * 40 + q * 8];
      acc[nt] = __builtin_amdgcn_mfma_f32_16x16x32_bf16(a, b, acc[nt], 0, 0, 0);
    }
    __syncthreads();
  }
  // epilogue: D layout col=lane&15, row=4*quad+r
  const int rowbase = m0 + 16 * w + 4 * q;
  #pragma unroll
  for (int nt = 0; nt < 32; ++nt){
    int col = 16 * nt + nl;
    float bc = bias[col];
    #pragma unroll
    for (int r = 0; r < 4; ++r)
      xin[(size_t)(rowbase + r) * D + col] = f2bf(acc[nt][r] + bc);
  }
}

// ---------------------------------------------------------------------------
// Kernel 2: the recurrence. 64 blocks = 16 groups (16 batch rows each) x 4
// column-slices of Wh (128 cols). Wh slice lives in REGISTERS (128 VGPR/lane)
// for all 512 steps. Per step: stage h(t-1) [16x512] bf16 -> LDS, MFMA
// (Wh_slice^T x h^T so lanes own 4 consecutive h columns), tanh, agent-scope
// packed stores + flag; peers spin on flags. Max skew 1 -> double buffer.
// ---------------------------------------------------------------------------
__launch_bounds__(256, 1)
__global__ void k_rnn(const u16* __restrict__ xin, const u16* __restrict__ Wht,
                      u16* __restrict__ hbuf, float* __restrict__ hlast,
                      int* __restrict__ flags){
  __shared__ __align__(16) u16 h_s[16 * 512];    // 16 KB, XOR-chunk-swizzled
  const int tid  = threadIdx.x;
  const int lane = tid & 63, w = tid >> 6;       // 4 waves
  const int nl   = lane & 15, q = lane >> 4;
  const int g    = blockIdx.x & 15;              // group (same XCD heuristic: stride-16 ids)
  const int j    = blockIdx.x >> 4;              // 0..3 column-slice
  const int colbase  = j * 128 + w * 32;         // this wave's 32 Wh-columns
  const int growbase = g * 16;                   // batch rows 16g..16g+15

  // Preload Wh A-fragments: A[m][k] = Wh[k][colbase+mt*16+m] = Wht[col][k]
  s16x8 whA[2][16];
  #pragma unroll
  for (int mt = 0; mt < 2; ++mt){
    const u16* wrow = Wht + (size_t)(colbase + mt * 16 + nl) * D;
    #pragma unroll
    for (int kc = 0; kc < 16; ++kc)
      whA[mt][kc] = *(const s16x8*)(wrow + kc * 32 + q * 8);
  }

  for (int t = 0; t < LSEQ; ++t){
    const int sw = t & 1, sr = sw ^ 1;
    if (t > 0){
      const int* fl = flags + (t - 1) * 64 + g * 4;
      for (;;){
        int s0 = __hip_atomic_load(fl + 0, __ATOMIC_RELAXED, __HIP_MEMORY_SCOPE_AGENT);
        int s1 = __hip_atomic_load(fl + 1, __ATOMIC_RELAXED, __HIP_MEMORY_SCOPE_AGENT);
        int s2 = __hip_atomic_load(fl + 2, __ATOMIC_RELAXED, __HIP_MEMORY_SCOPE_AGENT);
        int s3 = __hip_atomic_load(fl + 3, __ATOMIC_RELAXED, __HIP_MEMORY_SCOPE_AGENT);
        if (s0 & s1 & s2 & s3) break;
        __builtin_amdgcn_s_sleep(1);
      }
      __builtin_amdgcn_fence(__ATOMIC_ACQUIRE, "agent");
    }
    // stage h(t-1): wave w loads rows {w, w+4, w+8, w+12}, 1KB coalesced each
    {
      const u16* src = hbuf + (size_t)sr * (BATCH * D);
      #pragma unroll
      for (int i = 0; i < 4; ++i){
        int m = w + 4 * i;
        int c = lane;                              // 16B chunk index 0..63
        uint4 v = *(const uint4*)(src + (growbase + m) * D + c * 8);
        int p = c ^ (m & 7);                       // XOR swizzle (2-way max on read)
        *(uint4*)&h_s[m * 512 + p * 8] = v;
      }
    }
    __syncthreads();
    // acc init from xin: lane holds batch row nl, 4 consecutive cols (D rows)
    f32x4 acc[2];
    const size_t xrow = ((size_t)t * BATCH + growbase + nl) * D;
    #pragma unroll
    for (int mt = 0; mt < 2; ++mt){
      const u16* xp = xin + xrow + colbase + mt * 16 + 4 * q;
      #pragma unroll
      for (int r = 0; r < 4; ++r) acc[mt][r] = bf2f(xp[r]);
    }
    // K loop: B[k][n] = h[batch n][k] from LDS; A = resident Wh fragments
    #pragma unroll
    for (int kc = 0; kc < 16; ++kc){
      int c = kc * 4 + q;
      int p = c ^ (nl & 7);
      s16x8 hB = *(const s16x8*)&h_s[nl * 512 + p * 8];
      acc[0] = __builtin_amdgcn_mfma_f32_16x16x32_bf16(whA[0][kc], hB, acc[0], 0, 0, 0);
      acc[1] = __builtin_amdgcn_mfma_f32_16x16x32_bf16(whA[1][kc], hB, acc[1], 0, 0, 0);
    }
    // tanh + packed agent-scope stores (2x u32 per tile = 4 consecutive cols)
    u16* dst = hbuf + (size_t)sw * (BATCH * D) + (growbase + nl) * D;
    #pragma unroll
    for (int mt = 0; mt < 2; ++mt){
      float v0 = fast_tanh(acc[mt][0]);
      float v1 = fast_tanh(acc[mt][1]);
      float v2 = fast_tanh(acc[mt][2]);
      float v3 = fast_tanh(acc[mt][3]);
      int cb = colbase + mt * 16 + 4 * q;
      uint32_t w0 = (uint32_t)f2bf(v0) | ((uint32_t)f2bf(v1) << 16);
      uint32_t w1 = (uint32_t)f2bf(v2) | ((uint32_t)f2bf(v3) << 16);
      __hip_atomic_store((uint32_t*)(dst + cb),     w0, __ATOMIC_RELAXED, __HIP_MEMORY_SCOPE_AGENT);
      __hip_atomic_store((uint32_t*)(dst + cb + 2), w1, __ATOMIC_RELAXED, __HIP_MEMORY_SCOPE_AGENT);
      if (t == LSEQ - 1){
        float* hd = hlast + (size_t)(growbase + nl) * D + cb;
        hd[0] = v0; hd[1] = v1; hd[2] = v2; hd[3] = v3;
      }
    }
    __syncthreads();   // drains every thread's vmcnt before barrier -> stores agent-visible
    if (tid == 0)
      __hip_atomic_store(flags + t * 64 + g * 4 + j, 1, __ATOMIC_RELEASE, __HIP_MEMORY_SCOPE_AGENT);
  }
}

// ---------------------------------------------------------------------------
// Kernel 3: logits = h_last @ Wd + bd; softmax. One wave per batch row.
// ---------------------------------------------------------------------------
__global__ void k_head(const float* __restrict__ hlast, const float* __restrict__ Wd,
                       const float* __restrict__ bd, float* __restrict__ out){
  const int b = blockIdx.x;
  const int lane = threadIdx.x;          // 64 threads = 1 wave
  const float* hr = hlast + (size_t)b * D + lane * 8;
  float hv[8];
  #pragma unroll
  for (int i = 0; i < 8; ++i) hv[i] = hr[i];
  float acc[NCLS];
  #pragma unroll
  for (int c = 0; c < NCLS; ++c) acc[c] = 0.0f;
  #pragma unroll
  for (int i = 0; i < 8; ++i){
    const float* wr = Wd + (size_t)(lane * 8 + i) * NCLS;
    #pragma unroll
    for (int c = 0; c < NCLS; ++c) acc[c] += hv[i] * wr[c];
  }
  #pragma unroll
  for (int off = 32; off >= 1; off >>= 1){
    #pragma unroll
    for (int c = 0; c < NCLS; ++c) acc[c] += __shfl_xor(acc[c], off, 64);
  }
  float mx = -1e30f;
  #pragma unroll
  for (int c = 0; c < NCLS; ++c){ acc[c] += bd[c]; mx = fmaxf(mx, acc[c]); }
  float e[NCLS]; float s = 0.0f;
  #pragma unroll
  for (int c = 0; c < NCLS; ++c){
    e[c] = __builtin_amdgcn_exp2f((acc[c] - mx) * 1.4426950408889634f);
    s += e[c];
  }
  if (lane < NCLS) out[b * NCLS + lane] = e[lane] / s;
}

// ---------------------------------------------------------------------------
extern "C" void kernel_launch(void* const* d_in, const int* in_sizes, int n_in,
                              void* d_out, int out_size, void* d_ws, size_t ws_size,
                              hipStream_t stream){
  const int*   x    = (const int*)  d_in[0];
  const float* emb  = (const float*)d_in[1];
  const float* Wx   = (const float*)d_in[2];
  const float* Wh   = (const float*)d_in[3];
  const float* bias = (const float*)d_in[4];
  const float* Wd   = (const float*)d_in[5];
  const float* bd   = (const float*)d_in[6];
  float* out = (float*)d_out;
  char* ws = (char*)d_ws;

  const size_t XIN_B  = (size_t)LSEQ * BATCH * D * 2;   // 134217728
  const size_t W_B    = (size_t)D * D * 2;              // 524288
  const size_t HBUF_B = (size_t)2 * BATCH * D * 2;      // 524288
  const size_t HL_B   = (size_t)BATCH * D * 4;          // 524288
  const size_t FLG_B  = (size_t)LSEQ * 64 * 4;          // 131072

  u16*   xin   = (u16*)  (ws);
  u16*   Wxt   = (u16*)  (ws + XIN_B);
  u16*   Wht   = (u16*)  (ws + XIN_B + W_B);
  u16*   hbuf  = (u16*)  (ws + XIN_B + 2 * W_B);
  float* hlast = (float*)(ws + XIN_B + 2 * W_B + HBUF_B);
  int*   flags = (int*)  (ws + XIN_B + 2 * W_B + HBUF_B + HL_B);
  (void)in_sizes; (void)n_in; (void)out_size; (void)ws_size;

  // zero h0 (slot 1 read at t=0), h_last, flags — re-runs on every graph replay
  hipMemsetAsync(hbuf, 0, HBUF_B + HL_B + FLG_B, stream);

  k_transpose_cvt<<<dim3(1024), dim3(256), 0, stream>>>(Wx, Wh, Wxt, Wht);
  k_xin          <<<dim3(2048), dim3(256), 0, stream>>>(x, emb, Wxt, bias, xin);
  k_rnn          <<<dim3(64),   dim3(256), 0, stream>>>(xin, Wht, hbuf, hlast, flags);
  k_head         <<<dim3(256),  dim3(64),  0, stream>>>(hlast, Wd, bd, out);
}

// Round 2
// 1420.237 us; speedup vs baseline: 1.7974x; 1.7974x over previous
//
#include <hip/hip_runtime.h>
#include <stdint.h>

// Problem constants (SimpleRNN reference)
#define VOCAB 50000
#define D     512
#define LSEQ  512
#define BATCH 256
#define NCLS  20

typedef unsigned short u16;
using f32x4 = __attribute__((ext_vector_type(4))) float;
using s16x8 = __attribute__((ext_vector_type(8))) short;
using u32x2 = __attribute__((ext_vector_type(2))) unsigned int;
using u32x4 = __attribute__((ext_vector_type(4))) unsigned int;
using i32x4 = __attribute__((ext_vector_type(4))) int;

__device__ __forceinline__ float bf2f(u16 u){
  union { uint32_t i; float f; } v; v.i = ((uint32_t)u) << 16; return v.f;
}
__device__ __forceinline__ u16 f2bf(float f){
  uint32_t x = __float_as_uint(f);
  x += 0x7fffu + ((x >> 16) & 1u);          // RNE (values are tame, no NaN path)
  return (u16)(x >> 16);
}
__device__ __forceinline__ float bflo(uint32_t u){ return __uint_as_float(u << 16); }
__device__ __forceinline__ float bfhi(uint32_t u){ return __uint_as_float(u & 0xffff0000u); }
// tanh via v_exp_f32 + v_rcp_f32 (~5 VALU ops); saturates correctly at +/-inf.
__device__ __forceinline__ float fast_tanh(float x){
  float e = __builtin_amdgcn_exp2f(x * 2.8853900817779268f);   // e^(2x)
  return 1.0f - 2.0f * __builtin_amdgcn_rcpf(1.0f + e);
}

// Coherence-point (LLC) accesses: sc0 sc1 bypass L1 + per-XCD L2, so cross-XCD
// producer/consumer needs NO fences (no buffer_inv / buffer_wbl2 per step).
__device__ __forceinline__ void store_llc8(void* p, u32x2 v){
  asm volatile("global_store_dwordx2 %0, %1, off sc0 sc1" :: "v"(p), "v"(v) : "memory");
}
__device__ __forceinline__ void store_llc4(void* p, unsigned int v){
  asm volatile("global_store_dword %0, %1, off sc0 sc1" :: "v"(p), "v"(v) : "memory");
}
__device__ __forceinline__ void waitcnt_vm0(){
  asm volatile("s_waitcnt vmcnt(0)" ::: "memory");
}

// ---------------------------------------------------------------------------
// Kernel 0: transpose + bf16-convert Wx and Wh -> Wxt/Wht [n][k] layout so
// MFMA B/A fragments (8 contiguous k per lane) are 16B vector loads.
// ---------------------------------------------------------------------------
__global__ void k_transpose_cvt(const float* __restrict__ Wx, const float* __restrict__ Wh,
                                u16* __restrict__ Wxt, u16* __restrict__ Wht){
  const int n = blockIdx.x & 511;
  const float* src = (blockIdx.x >> 9) ? Wh : Wx;
  u16* dst = (blockIdx.x >> 9) ? Wht : Wxt;
  for (int k = threadIdx.x; k < D; k += blockDim.x)
    dst[n * D + k] = f2bf(src[k * D + n]);   // strided read, coalesced write; ~1.5MB total
}

// ---------------------------------------------------------------------------
// Kernel 1: xin[l][b][:] = emb[x[b][l]] @ Wx + b   (stored bf16, [L][B][D])
// ---------------------------------------------------------------------------
__launch_bounds__(256, 2)
__global__ void k_xin(const int* __restrict__ x, const float* __restrict__ emb,
                      const u16* __restrict__ Wxt, const float* __restrict__ bias,
                      u16* __restrict__ xin){
  __shared__ __align__(16) u16 Bt_s[512 * 40];   // [n][32k + 8 pad] bf16, 40KB
  __shared__ int tok_s[64];
  const int tid  = threadIdx.x;
  const int lane = tid & 63, w = tid >> 6;
  const int nl   = lane & 15, q = lane >> 4;
  const int m0   = blockIdx.x * 64;

  if (tid < 64){
    int R = m0 + tid;                 // global row = l*256 + b
    int l = R >> 8, b = R & 255;
    tok_s[tid] = x[b * LSEQ + l];     // x is [B][L]
  }
  f32x4 acc[32];
  #pragma unroll
  for (int i = 0; i < 32; ++i) acc[i] = (f32x4)0.0f;
  __syncthreads();

  const int myrow = 16 * w + nl;                  // A-row m this lane feeds
  const float* arow = emb + (size_t)tok_s[myrow] * D;

  for (int kc = 0; kc < 16; ++kc){
    #pragma unroll
    for (int i = 0; i < 8; ++i){
      int idx = tid + 256 * i;
      int r = idx >> 2, cc = idx & 3;
      *(uint4*)&Bt_s[r * 40 + cc * 8] = *(const uint4*)(Wxt + r * D + kc * 32 + cc * 8);
    }
    __syncthreads();
    float4 f0 = *(const float4*)(arow + kc * 32 + q * 8);
    float4 f1 = *(const float4*)(arow + kc * 32 + q * 8 + 4);
    s16x8 a;
    a[0]=(short)f2bf(f0.x); a[1]=(short)f2bf(f0.y); a[2]=(short)f2bf(f0.z); a[3]=(short)f2bf(f0.w);
    a[4]=(short)f2bf(f1.x); a[5]=(short)f2bf(f1.y); a[6]=(short)f2bf(f1.z); a[7]=(short)f2bf(f1.w);
    #pragma unroll
    for (int nt = 0; nt < 32; ++nt){
      s16x8 b = *(const s16x8*)&Bt_s[(16 * nt + nl) * 40 + q * 8];
      acc[nt] = __builtin_amdgcn_mfma_f32_16x16x32_bf16(a, b, acc[nt], 0, 0, 0);
    }
    __syncthreads();
  }
  const int rowbase = m0 + 16 * w + 4 * q;
  #pragma unroll
  for (int nt = 0; nt < 32; ++nt){
    int col = 16 * nt + nl;
    float bc = bias[col];
    #pragma unroll
    for (int r = 0; r < 4; ++r)
      xin[(size_t)(rowbase + r) * D + col] = f2bf(acc[nt][r] + bc);
  }
}

// ---------------------------------------------------------------------------
// Kernel 2: recurrence. 64 blocks = 16 groups (16 batch rows) x 4 col-slices
// (128 cols of Wh resident in regs/AGPRs). Per step: poll peers' flags (one
// coherent dwordx4), stage h(t-1) via LLC loads -> LDS, MFMA, tanh, LLC
// stores, vmcnt(0), barrier, flag store. NO acquire/release fences.
// ---------------------------------------------------------------------------
__launch_bounds__(256, 1)
__global__ void k_rnn(const u16* __restrict__ xin, const u16* __restrict__ Wht,
                      u16* __restrict__ hbuf, float* __restrict__ hlast,
                      int* __restrict__ flags){
  __shared__ __align__(16) u16 h_s[16 * 520];    // row stride 520 u16: bank-uniform
  const int tid  = threadIdx.x;
  const int lane = tid & 63, w = tid >> 6;       // 4 waves
  const int nl   = lane & 15, q = lane >> 4;
  const int g    = blockIdx.x & 15;              // batch group
  const int j    = blockIdx.x >> 4;              // 0..3 column-slice
  const int colbase  = j * 128 + w * 32;         // this wave's 32 Wh-columns
  const int growbase = g * 16;                   // batch rows 16g..16g+15

  // Preload Wh A-fragments: A[m][k] = Wh[k][colbase+mt*16+m] = Wht[col][k]
  s16x8 whA[2][16];
  #pragma unroll
  for (int mt = 0; mt < 2; ++mt){
    const u16* wrow = Wht + (size_t)(colbase + mt * 16 + nl) * D;
    #pragma unroll
    for (int kc = 0; kc < 16; ++kc)
      whA[mt][kc] = *(const s16x8*)(wrow + kc * 32 + q * 8);
  }

  for (int t = 0; t < LSEQ; ++t){
    const int sw = t & 1, sr = sw ^ 1;

    // xin prefetch (plain cached loads; independent of h)
    const size_t xrow = ((size_t)t * BATCH + growbase + nl) * D;
    uint2 xa = *(const uint2*)(xin + xrow + colbase + 4 * q);
    uint2 xb = *(const uint2*)(xin + xrow + colbase + 16 + 4 * q);

    if (t > 0){
      const int* fl = flags + (t - 1) * 64 + g * 4;
      for (;;){
        i32x4 f;
        asm volatile("global_load_dwordx4 %0, %1, off sc0 sc1\n\t"
                     "s_waitcnt vmcnt(0)"
                     : "=&v"(f) : "v"(fl) : "memory");
        if ((f[0] & f[1] & f[2] & f[3]) != 0) break;
        __builtin_amdgcn_s_sleep(1);
      }
    }

    // stage h(t-1): wave w loads rows {w,w+4,w+8,w+12} via LLC, one waitcnt
    {
      const u16* src = hbuf + (size_t)sr * (BATCH * D) + growbase * D;
      const u16* p0 = src + (w     ) * D + lane * 8;
      const u16* p1 = src + (w +  4) * D + lane * 8;
      const u16* p2 = src + (w +  8) * D + lane * 8;
      const u16* p3 = src + (w + 12) * D + lane * 8;
      u32x4 h0, h1, h2, h3;
      asm volatile("global_load_dwordx4 %0, %4, off sc0 sc1\n\t"
                   "global_load_dwordx4 %1, %5, off sc0 sc1\n\t"
                   "global_load_dwordx4 %2, %6, off sc0 sc1\n\t"
                   "global_load_dwordx4 %3, %7, off sc0 sc1\n\t"
                   "s_waitcnt vmcnt(0)"
                   : "=&v"(h0), "=&v"(h1), "=&v"(h2), "=&v"(h3)
                   : "v"(p0), "v"(p1), "v"(p2), "v"(p3) : "memory");
      *(u32x4*)&h_s[(w     ) * 520 + lane * 8] = h0;
      *(u32x4*)&h_s[(w +  4) * 520 + lane * 8] = h1;
      *(u32x4*)&h_s[(w +  8) * 520 + lane * 8] = h2;
      *(u32x4*)&h_s[(w + 12) * 520 + lane * 8] = h3;
    }
    __syncthreads();

    // acc init from xin (bf16 -> f32)
    f32x4 acc[2];
    acc[0][0] = bflo(xa.x); acc[0][1] = bfhi(xa.x); acc[0][2] = bflo(xa.y); acc[0][3] = bfhi(xa.y);
    acc[1][0] = bflo(xb.x); acc[1][1] = bfhi(xb.x); acc[1][2] = bflo(xb.y); acc[1][3] = bfhi(xb.y);

    // K loop: B[k][n] = h[batch n][k] from LDS; A = resident Wh fragments
    #pragma unroll
    for (int kc = 0; kc < 16; ++kc){
      s16x8 hB = *(const s16x8*)&h_s[nl * 520 + kc * 32 + q * 8];
      acc[0] = __builtin_amdgcn_mfma_f32_16x16x32_bf16(whA[0][kc], hB, acc[0], 0, 0, 0);
      acc[1] = __builtin_amdgcn_mfma_f32_16x16x32_bf16(whA[1][kc], hB, acc[1], 0, 0, 0);
    }

    // tanh + packed LLC stores (one dwordx2 per m-tile)
    u16* dst = hbuf + (size_t)sw * (BATCH * D) + (growbase + nl) * D;
    #pragma unroll
    for (int mt = 0; mt < 2; ++mt){
      float v0 = fast_tanh(acc[mt][0]);
      float v1 = fast_tanh(acc[mt][1]);
      float v2 = fast_tanh(acc[mt][2]);
      float v3 = fast_tanh(acc[mt][3]);
      int cb = colbase + mt * 16 + 4 * q;
      u32x2 pk;
      pk[0] = (uint32_t)f2bf(v0) | ((uint32_t)f2bf(v1) << 16);
      pk[1] = (uint32_t)f2bf(v2) | ((uint32_t)f2bf(v3) << 16);
      store_llc8(dst + cb, pk);
      if (t == LSEQ - 1){
        float* hd = hlast + (size_t)(growbase + nl) * D + cb;
        hd[0] = v0; hd[1] = v1; hd[2] = v2; hd[3] = v3;
      }
    }
    waitcnt_vm0();       // h stores acked at coherence point
    __syncthreads();     // all 256 threads' stores done + h_s reads done
    if (tid == 0)
      store_llc4(flags + t * 64 + g * 4 + j, 1);
  }
}

// ---------------------------------------------------------------------------
// Kernel 3: logits = h_last @ Wd + bd; softmax. One wave per batch row.
// ---------------------------------------------------------------------------
__global__ void k_head(const float* __restrict__ hlast, const float* __restrict__ Wd,
                       const float* __restrict__ bd, float* __restrict__ out){
  const int b = blockIdx.x;
  const int lane = threadIdx.x;          // 64 threads = 1 wave
  const float* hr = hlast + (size_t)b * D + lane * 8;
  float hv[8];
  #pragma unroll
  for (int i = 0; i < 8; ++i) hv[i] = hr[i];
  float acc[NCLS];
  #pragma unroll
  for (int c = 0; c < NCLS; ++c) acc[c] = 0.0f;
  #pragma unroll
  for (int i = 0; i < 8; ++i){
    const float* wr = Wd + (size_t)(lane * 8 + i) * NCLS;
    #pragma unroll
    for (int c = 0; c < NCLS; ++c) acc[c] += hv[i] * wr[c];
  }
  #pragma unroll
  for (int off = 32; off >= 1; off >>= 1){
    #pragma unroll
    for (int c = 0; c < NCLS; ++c) acc[c] += __shfl_xor(acc[c], off, 64);
  }
  float mx = -1e30f;
  #pragma unroll
  for (int c = 0; c < NCLS; ++c){ acc[c] += bd[c]; mx = fmaxf(mx, acc[c]); }
  float e[NCLS]; float s = 0.0f;
  #pragma unroll
  for (int c = 0; c < NCLS; ++c){
    e[c] = __builtin_amdgcn_exp2f((acc[c] - mx) * 1.4426950408889634f);
    s += e[c];
  }
  if (lane < NCLS) out[b * NCLS + lane] = e[lane] / s;
}

// ---------------------------------------------------------------------------
extern "C" void kernel_launch(void* const* d_in, const int* in_sizes, int n_in,
                              void* d_out, int out_size, void* d_ws, size_t ws_size,
                              hipStream_t stream){
  const int*   x    = (const int*)  d_in[0];
  const float* emb  = (const float*)d_in[1];
  const float* Wx   = (const float*)d_in[2];
  const float* Wh   = (const float*)d_in[3];
  const float* bias = (const float*)d_in[4];
  const float* Wd   = (const float*)d_in[5];
  const float* bd   = (const float*)d_in[6];
  float* out = (float*)d_out;
  char* ws = (char*)d_ws;

  const size_t XIN_B  = (size_t)LSEQ * BATCH * D * 2;   // 134217728
  const size_t W_B    = (size_t)D * D * 2;              // 524288
  const size_t HBUF_B = (size_t)2 * BATCH * D * 2;      // 524288
  const size_t HL_B   = (size_t)BATCH * D * 4;          // 524288
  const size_t FLG_B  = (size_t)LSEQ * 64 * 4;          // 131072

  u16*   xin   = (u16*)  (ws);
  u16*   Wxt   = (u16*)  (ws + XIN_B);
  u16*   Wht   = (u16*)  (ws + XIN_B + W_B);
  u16*   hbuf  = (u16*)  (ws + XIN_B + 2 * W_B);
  float* hlast = (float*)(ws + XIN_B + 2 * W_B + HBUF_B);
  int*   flags = (int*)  (ws + XIN_B + 2 * W_B + HBUF_B + HL_B);
  (void)in_sizes; (void)n_in; (void)out_size; (void)ws_size;

  hipMemsetAsync(hbuf, 0, HBUF_B + HL_B + FLG_B, stream);

  k_transpose_cvt<<<dim3(1024), dim3(256), 0, stream>>>(Wx, Wh, Wxt, Wht);
  k_xin          <<<dim3(2048), dim3(256), 0, stream>>>(x, emb, Wxt, bias, xin);
  k_rnn          <<<dim3(64),   dim3(256), 0, stream>>>(xin, Wht, hbuf, hlast, flags);
  k_head         <<<dim3(256),  dim3(64),  0, stream>>>(hlast, Wd, bd, out);
}